// Round 8
// baseline (273.597 us; speedup 1.0000x reference)
//
#include <hip/hip_runtime.h>

#define N_NODES 100000
#define N_EDGES 1600000
#define D_FEAT  64

#define RSHIFT 7
#define RPB    128                              // rows per bucket (782 buckets -> 3.05 blocks/CU)
#define NBK    ((N_NODES + RPB - 1) / RPB)      // 782 row-buckets
#define CAP    2816                             // bucket edge capacity (even; mean 2048 + 5 sigma + pads)
#define EPB    4096                             // edges per bin block
#define KBLK   ((N_EDGES + EPB - 1) / EPB)      // 391 bin blocks
#define OROW   (NBK + 1)
#define CVB    ((N_NODES * D_FEAT / 4 + 1023) / 1024)  // 1563 convert blocks

typedef float f32x2 __attribute__((ext_vector_type(2)));

__device__ __forceinline__ unsigned short f2bf(float f) {
  union { float f; unsigned int i; } v; v.f = f;
  unsigned int b = v.i;
  return (unsigned short)((b + 0x7FFFu + ((b >> 16) & 1u)) >> 16);  // RNE
}
__device__ __forceinline__ float ulo(int u) { return __int_as_float(u << 16); }
__device__ __forceinline__ float uhi(int u) { return __int_as_float(u & 0xFFFF0000); }
__device__ __forceinline__ f32x2 upk(int u) {  // {elem0, elem1} of a bf16 pair
  f32x2 r; r.x = ulo(u); r.y = uhi(u); return r;
}
__device__ __forceinline__ int pk(float a, float b) {
  return (int)f2bf(a) | ((int)f2bf(b) << 16);
}

// ---- fused pass 1: blocks [0,KBLK) bin edges into per-block bucket-sorted
// segments AND count edges per row (global gcnt, used by build_csr so it
// needs no histogram sweep); blocks [KBLK, KBLK+CVB) convert x to bf16.
__global__ __launch_bounds__(1024) void convert_bin(
    const float4* __restrict__ xin, ushort4* __restrict__ xout,
    const int* __restrict__ erow, const int* __restrict__ ecol,
    const float* __restrict__ evals, int2* __restrict__ tmp,
    int* __restrict__ offs, int* __restrict__ gcnt) {
  __shared__ int hist[NBK];
  __shared__ int sc[NBK];
  int t = threadIdx.x;
  int k = blockIdx.x;
  if (k >= KBLK) {                       // ---- convert path ----
    int i = (k - KBLK) * 1024 + t;
    if (i < N_NODES * D_FEAT / 4) {
      float4 v = xin[i];
      ushort4 o;
      o.x = f2bf(v.x); o.y = f2bf(v.y); o.z = f2bf(v.z); o.w = f2bf(v.w);
      xout[i] = o;
    }
    return;
  }
  // ---- bin path: block-local counting sort of 4096 edges by bucket ----
  if (t < NBK) hist[t] = 0;
  __syncthreads();
  int base = k * EPB;
  int nk = N_EDGES - base; if (nk > EPB) nk = EPB;
  int key[4], vb[4], rk[4], bk[4];
#pragma unroll
  for (int j = 0; j < 4; ++j) {
    int li = j * 1024 + t;
    bk[j] = -1;
    if (li < nk) {
      int e = base + li;
      int r = erow[e];
      key[j] = ((r & (RPB - 1)) << 17) | ecol[e];
      vb[j]  = __float_as_int(evals[e]);
      bk[j]  = r >> RSHIFT;
      rk[j]  = atomicAdd(&hist[bk[j]], 1);
      atomicAdd(&gcnt[r], 1);            // per-row count for build_csr
    }
  }
  __syncthreads();
  if (t < NBK) sc[t] = hist[t];
  __syncthreads();
  for (int off = 1; off < NBK; off <<= 1) {
    int u = (t >= off && t < NBK) ? sc[t - off] : 0;
    __syncthreads();
    if (t < NBK) sc[t] += u;
    __syncthreads();
  }
  if (t < NBK) {
    int ex = sc[t] - hist[t];
    sc[t] = ex;
    offs[k * OROW + t] = ex;
  }
  if (t == 0) offs[k * OROW + NBK] = nk;
  __syncthreads();
#pragma unroll
  for (int j = 0; j < 4; ++j) {
    if (bk[j] >= 0) {
      int pos = sc[bk[j]] + rk[j];
      tmp[k * EPB + pos] = make_int2(key[j], vb[j]);
    }
  }
}

// ---- pass 2: SINGLE sweep. Row lengths come from gcnt (no histogram pass):
// scan 128 even-padded lengths in LDS, then scatter the bucket's edges from
// the binned segments into their final row runs. Rows padded to EVEN edge
// counts so every row starts 16B-aligned (pad edge {0,0} adds nothing).
__global__ __launch_bounds__(256) void build_csr(
    const int2* __restrict__ tmp, const int* __restrict__ offs,
    const int* __restrict__ gcnt, int2* __restrict__ edges,
    int* __restrict__ row_beg, int* __restrict__ row_end) {
  __shared__ int cur[RPB];
  __shared__ int sc[RPB];
  int b = blockIdx.x;
  int t = threadIdx.x;
  int v = 0, v2 = 0;
  if (t < RPB) {
    int g = b * RPB + t;
    v = (g < N_NODES) ? gcnt[g] : 0;
    v2 = (v + 1) & ~1;                   // even-padded length
    sc[t] = v2;
  }
  __syncthreads();
  for (int off = 1; off < RPB; off <<= 1) {
    int u = (t >= off && t < RPB) ? sc[t - off] : 0;
    __syncthreads();
    if (t < RPB) sc[t] += u;
    __syncthreads();
  }
  if (t < RPB) {
    int excl2 = sc[t] - v2;
    cur[t] = excl2;
    int g = b * RPB + t;
    int base = b * CAP;
    if (g < N_NODES) {
      row_beg[g] = base + excl2;
      row_end[g] = base + excl2 + v;
    }
    if (v & 1) edges[base + excl2 + v] = make_int2(0, 0);  // zero pad slot
  }
  __syncthreads();
  int oct = t >> 3;        // 32 octets per block
  int ol  = t & 7;
  for (int k = oct; k < KBLK; k += 32) {
    int o0 = offs[k * OROW + b];
    int o1 = offs[k * OROW + b + 1];
    const int2* seg = tmp + k * EPB;
    for (int i = o0 + ol; i < o1; i += 8) {
      int2 ed = seg[i];
      int pos = atomicAdd(&cur[ed.x >> 17], 1);
      edges[b * CAP + pos] = make_int2(ed.x & 0x1FFFF, ed.y);
    }
  }
}

// ---- SpMM: ONE OCTET PER ROW (8 lanes x int4 = the full 128B feature row).
// 8 rows per wave, zero shuffles, zero LDS. Per edge pair: one int4
// octet-broadcast edge load + two int4 x-gathers; 2-pair unroll for MLP.
// (R0 structure, proven ~40us/layer = MSHR*latency bound; rounds 1-7 showed
// every restructuring loses more concurrency than it gains in latency.)
__global__ __launch_bounds__(256) void spmm_oct(
    const int* __restrict__ row_beg, const int* __restrict__ row_end,
    const int2* __restrict__ edges, const int4* __restrict__ xq,
    int4* __restrict__ h_q, float4* __restrict__ out,
    const int4* __restrict__ add1, const int4* __restrict__ add2,
    int final_mode) {
  int t = threadIdx.x;
  int lane = t & 63;
  int oct = lane >> 3;     // 0..7: row within wave
  int ol  = lane & 7;      // 0..7: which 16B of the 128B row
  int row = blockIdx.x * 32 + (t >> 6) * 8 + oct;   // grid exact: 3125*32=100000
  int e0 = row_beg[row];
  int e1 = row_end[row];
  const int4* ep = (const int4*)edges + (e0 >> 1);  // e0 even
  // Round UP: odd lengths include the (real, pad) pair; pad {0,0} adds 0.
  int npair = (e1 - e0 + 1) >> 1;
  f32x2 c0 = {0.f, 0.f}, c1 = {0.f, 0.f}, c2 = {0.f, 0.f}, c3 = {0.f, 0.f};

#define PAIR(m) { \
    int4 g0 = xq[(size_t)(m).x * 8 + ol]; \
    int4 g1 = xq[(size_t)(m).z * 8 + ol]; \
    float v0 = __int_as_float((m).y), v1 = __int_as_float((m).w); \
    f32x2 vv0 = {v0, v0}, vv1 = {v1, v1}; \
    c0 += vv0 * upk(g0.x) + vv1 * upk(g1.x); \
    c1 += vv0 * upk(g0.y) + vv1 * upk(g1.y); \
    c2 += vv0 * upk(g0.z) + vv1 * upk(g1.z); \
    c3 += vv0 * upk(g0.w) + vv1 * upk(g1.w); \
  }

  int p = 0;
  for (; p + 2 <= npair; p += 2) {   // 2 pairs = 4 edges: 6 loads in flight
    int4 m0 = ep[p];
    int4 m1 = ep[p + 1];
    PAIR(m0);
    PAIR(m1);
  }
  if (p < npair) {
    int4 m0 = ep[p];
    PAIR(m0);
  }
#undef PAIR

  size_t oi = (size_t)row * 8 + ol;
  if (final_mode) {
    int4 r1 = add1[oi];
    int4 r2 = add2[oi];
    float4 lo, hi;
    lo.x = c0.x + ulo(r1.x) + ulo(r2.x);
    lo.y = c0.y + uhi(r1.x) + uhi(r2.x);
    lo.z = c1.x + ulo(r1.y) + ulo(r2.y);
    lo.w = c1.y + uhi(r1.y) + uhi(r2.y);
    hi.x = c2.x + ulo(r1.z) + ulo(r2.z);
    hi.y = c2.y + uhi(r1.z) + uhi(r2.z);
    hi.z = c3.x + ulo(r1.w) + ulo(r2.w);
    hi.w = c3.y + uhi(r1.w) + uhi(r2.w);
    out[(size_t)row * 16 + ol * 2]     = lo;
    out[(size_t)row * 16 + ol * 2 + 1] = hi;
  } else {
    int4 pq;
    pq.x = pk(c0.x, c0.y);
    pq.y = pk(c1.x, c1.y);
    pq.z = pk(c2.x, c2.y);
    pq.w = pk(c3.x, c3.y);
    h_q[oi] = pq;
  }
}

extern "C" void kernel_launch(void* const* d_in, const int* in_sizes, int n_in,
                              void* d_out, int out_size, void* d_ws, size_t ws_size,
                              hipStream_t stream) {
  const float* x     = (const float*)d_in[0];
  const int*   erow  = (const int*)d_in[1];
  const int*   ecol  = (const int*)d_in[2];
  const float* evals = (const float*)d_in[3];
  float* out = (float*)d_out;

  const size_t hb_bytes   = (size_t)N_NODES * D_FEAT * 2;     // 12.8 MB (bf16)
  const size_t ecap_bytes = (size_t)NBK * CAP * sizeof(int2); // 17.6 MB
  char* ws = (char*)d_ws;
  int4* xbf   = (int4*)(ws);                       // 12.8 MB, live whole launch
  int4* bufA  = (int4*)(ws + hb_bytes);            // h1 (bf16)
  int2* tmp   = (int2*)(ws + hb_bytes);            // aliases bufA (build only)
  int4* bufB  = (int4*)(ws + 2 * hb_bytes);        // h2 (bf16)
  int*  offs  = (int*) (ws + 2 * hb_bytes);        // aliases bufB (1.2MB, build only)
  int2* edges = (int2*)(ws + 3 * hb_bytes);        // 17.6 MB row-sorted edges
  int*  row_beg = (int*)(ws + 3 * hb_bytes + ecap_bytes);
  int*  row_end = (int*)(ws + 3 * hb_bytes + ecap_bytes + 400000);
  int*  gcnt    = (int*)(ws + 3 * hb_bytes + ecap_bytes + 800000);

  const int sblocks = N_NODES / 32;                // 3125 (8 rows/wave)

  // ---- prep: zero row counters; fused bin+count+convert; single-sweep CSR --
  hipMemsetAsync(gcnt, 0, (size_t)N_NODES * sizeof(int), stream);
  convert_bin<<<KBLK + CVB, 1024, 0, stream>>>(
      (const float4*)x, (ushort4*)xbf, erow, ecol, evals, tmp, offs, gcnt);
  build_csr<<<NBK, 256, 0, stream>>>(tmp, offs, gcnt, edges, row_beg, row_end);

  // L1: bufA = bf16(A xbf)      (tmp dead after build)
  spmm_oct<<<sblocks, 256, 0, stream>>>(row_beg, row_end, edges, xbf,
                                        bufA, nullptr, nullptr, nullptr, 0);
  // L2: bufB = bf16(A bufA)     (offs dead)
  spmm_oct<<<sblocks, 256, 0, stream>>>(row_beg, row_end, edges, bufA,
                                        bufB, nullptr, nullptr, nullptr, 0);
  // L3: out = A bufB + bufA + bufB   (f32 output)
  spmm_oct<<<sblocks, 256, 0, stream>>>(row_beg, row_end, edges, bufB,
                                        nullptr, (float4*)out, bufA, bufB, 1);
}